// Round 1
// baseline (498.278 us; speedup 1.0000x reference)
//
#include <hip/hip_runtime.h>
#include <hip/hip_bf16.h>
#include <math.h>

#define N_TOK 16384
#define BATCH 4
#define DIM   1024
#define HID   256
#define KEEP  11468            // int(16384 * 0.7)
#define MROWS (N_TOK * BATCH)  // 65536

// ---------------------------------------------------------------------------
// Kernel 1: scores = sigmoid(relu(x @ W1 + b1) @ W2 + b2), fused, f32.
// Block: 256 threads. Tile: 64 rows x 256 cols (full H). DT=32 K-step.
// Thread (tc 0..63, tr 0..3): R=16 rows, C=4 cols -> acc[16][4].
// LDS: xs[dd][row] transposed (pad 68 for conflict-free-ish writes, reads are
// wave-uniform broadcasts), ws[dd][256] (b128 reads conflict-free across tc).
// ---------------------------------------------------------------------------
__global__ __launch_bounds__(256) void score_kernel(
    const float* __restrict__ x, const float* __restrict__ W1,
    const float* __restrict__ b1, const float* __restrict__ W2,
    const float* __restrict__ b2, float* __restrict__ scores,
    float* __restrict__ lossPartial)
{
    __shared__ float xs[32][68];
    __shared__ float wsm[32][256];
    __shared__ float sloc[64];

    const int t  = threadIdx.x;
    const int tc = t & 63;
    const int tr = t >> 6;          // wave id, 0..3
    const size_t row0 = (size_t)blockIdx.x * 64;

    float acc[16][4];
#pragma unroll
    for (int r = 0; r < 16; ++r)
#pragma unroll
        for (int c = 0; c < 4; ++c) acc[r][c] = 0.f;

    for (int d0 = 0; d0 < DIM; d0 += 32) {
        // stage x: 64 rows x 32 d's = 512 float4, 2 per thread, transposed store
#pragma unroll
        for (int it = 0; it < 2; ++it) {
            const int i  = t + it * 256;
            const int r  = i >> 3;          // 0..63
            const int c4 = (i & 7) * 4;     // 0,4,...,28
            const float4 v = *(const float4*)(x + (row0 + r) * DIM + d0 + c4);
            xs[c4 + 0][r] = v.x;
            xs[c4 + 1][r] = v.y;
            xs[c4 + 2][r] = v.z;
            xs[c4 + 3][r] = v.w;
        }
        // stage W1: 32 x 256 = 2048 float4, 8 per thread
#pragma unroll
        for (int it = 0; it < 8; ++it) {
            const int i  = t + it * 256;    // 0..2047
            const int dd = i >> 6;          // 0..31
            const int c4 = (i & 63) * 4;
            *(float4*)&wsm[dd][c4] = *(const float4*)(W1 + (size_t)(d0 + dd) * HID + c4);
        }
        __syncthreads();

#pragma unroll 4
        for (int dd = 0; dd < 32; ++dd) {
            float wr[4];
            *(float4*)wr = *(const float4*)&wsm[dd][tc * 4];
            const float* xp = &xs[dd][tr * 16];
            float xr[16];
            ((float4*)xr)[0] = *(const float4*)(xp + 0);
            ((float4*)xr)[1] = *(const float4*)(xp + 4);
            ((float4*)xr)[2] = *(const float4*)(xp + 8);
            ((float4*)xr)[3] = *(const float4*)(xp + 12);
#pragma unroll
            for (int r = 0; r < 16; ++r)
#pragma unroll
                for (int c = 0; c < 4; ++c)
                    acc[r][c] = fmaf(xr[r], wr[c], acc[r][c]);
        }
        __syncthreads();
    }

    // epilogue: h = relu(acc + b1), z-partial = h . W2, wave-reduce over tc
    const float4 b1v = *(const float4*)(b1 + tc * 4);
    const float4 w2v = *(const float4*)(W2 + tc * 4);
    float zr[16];
#pragma unroll
    for (int r = 0; r < 16; ++r) {
        const float h0 = fmaxf(acc[r][0] + b1v.x, 0.f);
        const float h1 = fmaxf(acc[r][1] + b1v.y, 0.f);
        const float h2 = fmaxf(acc[r][2] + b1v.z, 0.f);
        const float h3 = fmaxf(acc[r][3] + b1v.w, 0.f);
        zr[r] = fmaf(h0, w2v.x, fmaf(h1, w2v.y, fmaf(h2, w2v.z, h3 * w2v.w)));
    }
    const float bb2 = b2[0];
#pragma unroll
    for (int r = 0; r < 16; ++r) {
        float v = zr[r];
        v += __shfl_xor(v, 32);
        v += __shfl_xor(v, 16);
        v += __shfl_xor(v, 8);
        v += __shfl_xor(v, 4);
        v += __shfl_xor(v, 2);
        v += __shfl_xor(v, 1);
        if (tc == r) {
            const float z = v + bb2;
            const float s = 1.0f / (1.0f + expf(-z));
            scores[row0 + tr * 16 + r] = s;
            sloc[tr * 16 + r] = fabsf(s - 0.5f);
        }
    }
    __syncthreads();
    if (t == 0) {
        float sum = 0.f;
        for (int i = 0; i < 64; ++i) sum += sloc[i];
        lossPartial[blockIdx.x] = sum;
    }
}

// ---------------------------------------------------------------------------
// Kernel 2: exact top-k selection per batch (k largest scores, ties broken by
// lowest index), emitting index list already sorted ascending by index.
// One block per batch, 1024 threads, each holds 16 contiguous score-bits in
// registers. Binary search on IEEE bits (all scores in (0,1) -> positive ->
// bit pattern is order-isomorphic to value).
// ---------------------------------------------------------------------------
__global__ __launch_bounds__(1024) void select_kernel(
    const float* __restrict__ scores, int* __restrict__ idxList)
{
    const int b    = blockIdx.x;
    const int t    = threadIdx.x;
    const int lane = t & 63;
    const int wid  = t >> 6;   // 0..15
    __shared__ unsigned red[17];

    unsigned bits[16];
    const float4* sp = (const float4*)(scores + (size_t)b * N_TOK + t * 16);
#pragma unroll
    for (int j = 0; j < 4; ++j) {
        const float4 v = sp[j];
        bits[j * 4 + 0] = __float_as_uint(v.x);
        bits[j * 4 + 1] = __float_as_uint(v.y);
        bits[j * 4 + 2] = __float_as_uint(v.z);
        bits[j * 4 + 3] = __float_as_uint(v.w);
    }

    auto countGE = [&](unsigned v) -> unsigned {
        unsigned c = 0;
#pragma unroll
        for (int j = 0; j < 16; ++j) c += (bits[j] >= v) ? 1u : 0u;
        c += __shfl_xor(c, 32);
        c += __shfl_xor(c, 16);
        c += __shfl_xor(c, 8);
        c += __shfl_xor(c, 4);
        c += __shfl_xor(c, 2);
        c += __shfl_xor(c, 1);
        if (lane == 0) red[wid] = c;
        __syncthreads();
        if (t == 0) {
            unsigned s = 0;
            for (int w = 0; w < 16; ++w) s += red[w];
            red[16] = s;
        }
        __syncthreads();
        return red[16];
    };

    // find T = max{v : count(bits >= v) >= KEEP}
    unsigned lo = 0u, hi = 0x40000000u;   // scores strictly in (0,1)
    while (hi - lo > 1u) {
        const unsigned mid = (lo + hi) >> 1;
        const unsigned c = countGE(mid);
        if (c >= KEEP) lo = mid; else hi = mid;
    }
    const unsigned T   = lo;
    const unsigned cGT = countGE(T + 1u);
    const unsigned need = KEEP - cGT;     // ties at T to keep (lowest indices)

    // packed exclusive prefix: low 16 bits = #(>T) before i, high = #(==T) before i
    unsigned pre[16];
    unsigned run = 0;
#pragma unroll
    for (int j = 0; j < 16; ++j) {
        pre[j] = run;
        const unsigned gt = (bits[j] > T) ? 1u : 0u;
        const unsigned eq = (bits[j] == T) ? 1u : 0u;
        run += gt | (eq << 16);
    }
    unsigned inc = run;
#pragma unroll
    for (int off = 1; off < 64; off <<= 1) {
        const unsigned n = __shfl_up(inc, off);
        if (lane >= off) inc += n;
    }
    const unsigned waveExcl = inc - run;
    if (lane == 63) red[wid] = inc;
    __syncthreads();
    if (t == 0) {
        unsigned s = 0;
        for (int w = 0; w < 16; ++w) { const unsigned tmp = red[w]; red[w] = s; s += tmp; }
    }
    __syncthreads();
    const unsigned base = red[wid] + waveExcl;

#pragma unroll
    for (int j = 0; j < 16; ++j) {
        const unsigned pe    = base + pre[j];
        const unsigned tieR  = pe >> 16;
        const unsigned posGT = pe & 0xFFFFu;
        const bool gt = bits[j] > T;
        const bool eq = bits[j] == T;
        if (gt || (eq && tieR < need)) {
            const unsigned pos = posGT + (tieR < need ? tieR : need);
            idxList[(size_t)b * KEEP + pos] = t * 16 + j;
        }
    }
}

// ---------------------------------------------------------------------------
// Kernel 3: weighted gather. 4 output rows per 256-thread block, float4.
// ---------------------------------------------------------------------------
__global__ __launch_bounds__(256) void gather_kernel(
    const float* __restrict__ x, const float* __restrict__ scores,
    const int* __restrict__ idxList, float* __restrict__ out)
{
    const int t = threadIdx.x;
#pragma unroll
    for (int q = 0; q < 4; ++q) {
        const int orow = blockIdx.x * 4 + q;
        const int b    = orow / KEEP;
        const int idx  = idxList[orow];
        const float s  = scores[(size_t)b * N_TOK + idx];
        const float4 v = *(const float4*)(x + (((size_t)b * N_TOK + idx) << 10) + t * 4);
        float4 o;
        o.x = v.x * s; o.y = v.y * s; o.z = v.z * s; o.w = v.w * s;
        *(float4*)(out + ((size_t)orow << 10) + t * 4) = o;
    }
}

// ---------------------------------------------------------------------------
// Kernel 4: loss = -mean(|s - 0.5|), deterministic tree reduce of partials.
// ---------------------------------------------------------------------------
__global__ __launch_bounds__(256) void loss_kernel(
    const float* __restrict__ partials, float* __restrict__ outLoss)
{
    __shared__ float red[256];
    const int t = threadIdx.x;
    float s = partials[t] + partials[t + 256] + partials[t + 512] + partials[t + 768];
    red[t] = s;
    __syncthreads();
    for (int off = 128; off > 0; off >>= 1) {
        if (t < off) red[t] += red[t + off];
        __syncthreads();
    }
    if (t == 0) outLoss[0] = -(red[0] / (float)MROWS);
}

extern "C" void kernel_launch(void* const* d_in, const int* in_sizes, int n_in,
                              void* d_out, int out_size, void* d_ws, size_t ws_size,
                              hipStream_t stream)
{
    const float* x  = (const float*)d_in[0];
    const float* W1 = (const float*)d_in[1];
    const float* b1 = (const float*)d_in[2];
    const float* W2 = (const float*)d_in[3];
    const float* b2 = (const float*)d_in[4];
    float* out = (float*)d_out;

    float* scores   = (float*)d_ws;            // 65536 floats
    float* partials = scores + MROWS;          // 1024 floats
    int*   idxList  = (int*)(partials + 1024); // 45872 ints

    score_kernel<<<MROWS / 64, 256, 0, stream>>>(x, W1, b1, W2, b2, scores, partials);
    loss_kernel<<<1, 256, 0, stream>>>(partials, out + (size_t)BATCH * KEEP * DIM);
    select_kernel<<<BATCH, 1024, 0, stream>>>(scores, idxList);
    gather_kernel<<<KEEP, 256, 0, stream>>>(x, scores, idxList, out);
}

// Round 2
// 316.630 us; speedup vs baseline: 1.5737x; 1.5737x over previous
//
#include <hip/hip_runtime.h>
#include <hip/hip_bf16.h>
#include <math.h>

#define N_TOK 16384
#define BATCH 4
#define DIM   1024
#define HID   256
#define KEEP  11468            // int(16384 * 0.7)
#define MROWS (N_TOK * BATCH)  // 65536
#define NKT   (DIM / 32)       // 32 K-tiles
#define DELTA 3e-5f            // recompute window around the approx cut

typedef __attribute__((ext_vector_type(8))) short bf16x8;
typedef __attribute__((ext_vector_type(4))) float f32x4;

__device__ inline unsigned bf16_rne(float f) {
    unsigned u = __float_as_uint(f);
    return (u + 0x7FFFu + ((u >> 16) & 1u)) >> 16;
}

// ---------------------------------------------------------------------------
// prep: split W1 [1024][256] f32 into bf16 hi/lo, TILED layout:
// Wt[kt][h][kk]  (kt = k/32, kk = k%32) so each (kt) tile is 16KB contiguous.
// ---------------------------------------------------------------------------
__global__ __launch_bounds__(256) void prep_kernel(
    const float* __restrict__ W1, ushort* __restrict__ Wh, ushort* __restrict__ Wl)
{
    const int kt = blockIdx.x;   // 0..31
    const int h  = threadIdx.x;  // 0..255
    for (int kk = 0; kk < 32; ++kk) {
        const float w = W1[(size_t)(kt * 32 + kk) * HID + h];
        const unsigned hi = bf16_rne(w);
        const float fhi = __uint_as_float(hi << 16);
        const unsigned lo = bf16_rne(w - fhi);
        const size_t o = (size_t)kt * 8192 + (size_t)h * 32 + kk;
        Wh[o] = (ushort)hi;
        Wl[o] = (ushort)lo;
    }
}

// ---------------------------------------------------------------------------
// score_mfma: scores = sigmoid(relu(x@W1+b1)@W2+b2) with 3-pass bf16-split
// MFMA (xh*wh + xl*wh + xh*wl ~ f32 precision, rel err ~2^-18).
// Block 256 thr = 4 waves (2x2 over 128 rows x 256 cols). BK=32.
// LDS rows padded to 40 shorts (80B: 16B-aligned, ~2-way bank aliasing).
// ---------------------------------------------------------------------------
__global__ __launch_bounds__(256, 2) void score_mfma(
    const float* __restrict__ x, const ushort* __restrict__ Wh,
    const ushort* __restrict__ Wl, const float* __restrict__ b1,
    const float* __restrict__ W2, const float* __restrict__ b2,
    float* __restrict__ scores, float* __restrict__ partials)
{
    __shared__ ushort AsH[128 * 40], AsL[128 * 40];
    __shared__ ushort BsH[256 * 40], BsL[256 * 40];
    __shared__ float zbuf[128][2];
    __shared__ float red[128];

    const int t    = threadIdx.x;
    const int lane = t & 63;
    const int w    = t >> 6;
    const int wr   = w >> 1;          // wave row 0..1 (64 rows each)
    const int wc   = w & 1;           // wave col 0..1 (128 cols each)
    const int l15  = lane & 15;
    const int lk   = lane >> 4;       // k-group 0..3
    const size_t row0 = (size_t)blockIdx.x * 128;

    f32x4 acc[4][8];
#pragma unroll
    for (int rf = 0; rf < 4; ++rf)
#pragma unroll
        for (int cf = 0; cf < 8; ++cf) acc[rf][cf] = (f32x4){0.f, 0.f, 0.f, 0.f};

    // staging roles
    const int ar = t >> 1, ah = t & 1;   // A: row (0..127), 16-float half
    const int br = t >> 2, bp = t & 3;   // B: h row (0..255... br<256? t>>2: 0..63!)

    for (int kt = 0; kt < NKT; ++kt) {
        // ---- stage A: 128 rows x 32 k f32 -> bf16 hi/lo
        {
            const float* xp = x + (row0 + ar) * DIM + kt * 32 + ah * 16;
            float v[16];
            ((float4*)v)[0] = ((const float4*)xp)[0];
            ((float4*)v)[1] = ((const float4*)xp)[1];
            ((float4*)v)[2] = ((const float4*)xp)[2];
            ((float4*)v)[3] = ((const float4*)xp)[3];
            unsigned hi[16], lo[16];
#pragma unroll
            for (int j = 0; j < 16; ++j) {
                hi[j] = bf16_rne(v[j]);
                const float fh = __uint_as_float(hi[j] << 16);
                lo[j] = bf16_rne(v[j] - fh);
            }
            uint4 H0, H1, L0, L1;
            H0.x = hi[0] | (hi[1] << 16);  H0.y = hi[2] | (hi[3] << 16);
            H0.z = hi[4] | (hi[5] << 16);  H0.w = hi[6] | (hi[7] << 16);
            H1.x = hi[8] | (hi[9] << 16);  H1.y = hi[10] | (hi[11] << 16);
            H1.z = hi[12] | (hi[13] << 16); H1.w = hi[14] | (hi[15] << 16);
            L0.x = lo[0] | (lo[1] << 16);  L0.y = lo[2] | (lo[3] << 16);
            L0.z = lo[4] | (lo[5] << 16);  L0.w = lo[6] | (lo[7] << 16);
            L1.x = lo[8] | (lo[9] << 16);  L1.y = lo[10] | (lo[11] << 16);
            L1.z = lo[12] | (lo[13] << 16); L1.w = lo[14] | (lo[15] << 16);
            const int o = ar * 40 + ah * 16;
            *(uint4*)&AsH[o]     = H0;  *(uint4*)&AsH[o + 8] = H1;
            *(uint4*)&AsL[o]     = L0;  *(uint4*)&AsL[o + 8] = L1;
        }
        // ---- stage B: 256 h-rows x 32 k bf16 hi/lo (pre-split, tiled): each
        // thread copies 16B of 4 different h rows (t>>2 gives 64 rows; x4 loop)
        {
#pragma unroll
            for (int rr = 0; rr < 4; ++rr) {
                const int hh = br + rr * 64;     // 0..255
                const size_t wo = (size_t)kt * 8192 + (size_t)hh * 32 + bp * 8;
                const uint4 WH = *(const uint4*)(Wh + wo);
                const uint4 WL = *(const uint4*)(Wl + wo);
                const int o = hh * 40 + bp * 8;
                *(uint4*)&BsH[o] = WH;
                *(uint4*)&BsL[o] = WL;
            }
        }
        __syncthreads();

        // ---- compute: A-frags once, B-frags per cf, 3 MFMA per (rf,cf)
        bf16x8 Ah[4], Al[4];
#pragma unroll
        for (int rf = 0; rf < 4; ++rf) {
            const int ao = (wr * 64 + rf * 16 + l15) * 40 + lk * 8;
            Ah[rf] = *(const bf16x8*)&AsH[ao];
            Al[rf] = *(const bf16x8*)&AsL[ao];
        }
#pragma unroll
        for (int cf = 0; cf < 8; ++cf) {
            const int bo = (wc * 128 + cf * 16 + l15) * 40 + lk * 8;
            const bf16x8 Bh = *(const bf16x8*)&BsH[bo];
            const bf16x8 Bl = *(const bf16x8*)&BsL[bo];
#pragma unroll
            for (int rf = 0; rf < 4; ++rf) {
                acc[rf][cf] = __builtin_amdgcn_mfma_f32_16x16x32_bf16(Ah[rf], Bh, acc[rf][cf], 0, 0, 0);
                acc[rf][cf] = __builtin_amdgcn_mfma_f32_16x16x32_bf16(Al[rf], Bh, acc[rf][cf], 0, 0, 0);
                acc[rf][cf] = __builtin_amdgcn_mfma_f32_16x16x32_bf16(Ah[rf], Bl, acc[rf][cf], 0, 0, 0);
            }
        }
        __syncthreads();
    }

    // ---- epilogue: z = sum_h W2[h]*relu(C+b1[h]); C row=(lk*4+j), col=l15
    float b1r[8], w2r[8];
#pragma unroll
    for (int cf = 0; cf < 8; ++cf) {
        const int col = wc * 128 + cf * 16 + l15;
        b1r[cf] = b1[col];
        w2r[cf] = W2[col];
    }
#pragma unroll
    for (int rf = 0; rf < 4; ++rf) {
#pragma unroll
        for (int j = 0; j < 4; ++j) {
            float z = 0.f;
#pragma unroll
            for (int cf = 0; cf < 8; ++cf)
                z += fmaxf(acc[rf][cf][j] + b1r[cf], 0.f) * w2r[cf];
            z += __shfl_xor(z, 1);
            z += __shfl_xor(z, 2);
            z += __shfl_xor(z, 4);
            z += __shfl_xor(z, 8);
            if (l15 == 0) zbuf[wr * 64 + rf * 16 + lk * 4 + j][wc] = z;
        }
    }
    __syncthreads();
    if (t < 128) {
        const float z = zbuf[t][0] + zbuf[t][1] + b2[0];
        const float s = 1.f / (1.f + expf(-z));
        scores[row0 + t] = s;
        red[t] = fabsf(s - 0.5f);
    }
    __syncthreads();
    for (int off = 64; off > 0; off >>= 1) {
        if (t < off && t + off < 128) red[t] += red[t + off];
        __syncthreads();
    }
    if (t == 0) partials[blockIdx.x] = red[0];
}

// ---------------------------------------------------------------------------
// fix: per batch, find approx k-th score (bit binary search), recompute rows
// within +-DELTA of it exactly in f32, overwrite scores. Deterministic.
// ---------------------------------------------------------------------------
__global__ __launch_bounds__(1024) void fix_kernel(
    const float* __restrict__ x, const float* __restrict__ W1,
    const float* __restrict__ b1, const float* __restrict__ W2,
    const float* __restrict__ b2, float* __restrict__ scores)
{
    const int b    = blockIdx.x;
    const int t    = threadIdx.x;
    const int lane = t & 63;
    const int wid  = t >> 6;
    __shared__ unsigned red[17];
    __shared__ int counts[1024];
    __shared__ int wlist[64];
    __shared__ int wcnt;
    __shared__ float xr[1024];
    __shared__ float hp[4][256];
    __shared__ float zr[256];

    float sv[16];
    unsigned bits[16];
    const float4* sp = (const float4*)(scores + (size_t)b * N_TOK + t * 16);
#pragma unroll
    for (int j = 0; j < 4; ++j) {
        const float4 v = sp[j];
        sv[j * 4 + 0] = v.x; sv[j * 4 + 1] = v.y;
        sv[j * 4 + 2] = v.z; sv[j * 4 + 3] = v.w;
    }
#pragma unroll
    for (int j = 0; j < 16; ++j) bits[j] = __float_as_uint(sv[j]);

    auto countGE = [&](unsigned v) -> unsigned {
        unsigned c = 0;
#pragma unroll
        for (int j = 0; j < 16; ++j) c += (bits[j] >= v) ? 1u : 0u;
        c += __shfl_xor(c, 32); c += __shfl_xor(c, 16); c += __shfl_xor(c, 8);
        c += __shfl_xor(c, 4);  c += __shfl_xor(c, 2);  c += __shfl_xor(c, 1);
        if (lane == 0) red[wid] = c;
        __syncthreads();
        if (t == 0) {
            unsigned s = 0;
            for (int w2_ = 0; w2_ < 16; ++w2_) s += red[w2_];
            red[16] = s;
        }
        __syncthreads();
        const unsigned r = red[16];
        __syncthreads();
        return r;
    };

    unsigned lo = 0u, hi = 0x40000000u;
    while (hi - lo > 1u) {
        const unsigned mid = (lo + hi) >> 1;
        if (countGE(mid) >= KEEP) lo = mid; else hi = mid;
    }
    const float sT = __uint_as_float(lo);

    // deterministic window collection
    int c = 0;
#pragma unroll
    for (int j = 0; j < 16; ++j) c += (fabsf(sv[j] - sT) <= DELTA) ? 1 : 0;
    counts[t] = c;
    __syncthreads();
    if (t == 0) {
        int s = 0;
        for (int i = 0; i < 1024; ++i) { const int tmp = counts[i]; counts[i] = s; s += tmp; }
        wcnt = (s > 64) ? 64 : s;
    }
    __syncthreads();
    int base = counts[t];
#pragma unroll
    for (int j = 0; j < 16; ++j) {
        if (fabsf(sv[j] - sT) <= DELTA) {
            if (base < 64) wlist[base] = t * 16 + j;
            base++;
        }
    }
    __syncthreads();
    const int nw = wcnt;

    for (int wi = 0; wi < nw; ++wi) {
        const int row = wlist[wi];
        xr[t] = x[((size_t)b * N_TOK + row) * DIM + t];
        __syncthreads();
        const int h = t & 255, q = t >> 8;
        float p = 0.f;
        const int k0 = q * 256;
        for (int k = 0; k < 256; ++k) p = fmaf(xr[k0 + k], W1[(size_t)(k0 + k) * HID + h], p);
        hp[q][h] = p;
        __syncthreads();
        if (t < 256) {
            float hv = (hp[0][t] + hp[1][t]) + (hp[2][t] + hp[3][t]);
            hv = fmaxf(hv + b1[t], 0.f);
            zr[t] = hv * W2[t];
        }
        __syncthreads();
        for (int off = 128; off > 0; off >>= 1) {
            if (t < off) zr[t] += zr[t + off];
            __syncthreads();
        }
        if (t == 0) scores[(size_t)b * N_TOK + row] = 1.f / (1.f + expf(-(zr[0] + b2[0])));
        __syncthreads();
    }
}

// ---------------------------------------------------------------------------
// select: exact top-k per batch on (corrected) scores. Unchanged from round 1.
// ---------------------------------------------------------------------------
__global__ __launch_bounds__(1024) void select_kernel(
    const float* __restrict__ scores, int* __restrict__ idxList)
{
    const int b    = blockIdx.x;
    const int t    = threadIdx.x;
    const int lane = t & 63;
    const int wid  = t >> 6;
    __shared__ unsigned red[17];

    unsigned bits[16];
    const float4* sp = (const float4*)(scores + (size_t)b * N_TOK + t * 16);
#pragma unroll
    for (int j = 0; j < 4; ++j) {
        const float4 v = sp[j];
        bits[j * 4 + 0] = __float_as_uint(v.x);
        bits[j * 4 + 1] = __float_as_uint(v.y);
        bits[j * 4 + 2] = __float_as_uint(v.z);
        bits[j * 4 + 3] = __float_as_uint(v.w);
    }

    auto countGE = [&](unsigned v) -> unsigned {
        unsigned c = 0;
#pragma unroll
        for (int j = 0; j < 16; ++j) c += (bits[j] >= v) ? 1u : 0u;
        c += __shfl_xor(c, 32); c += __shfl_xor(c, 16); c += __shfl_xor(c, 8);
        c += __shfl_xor(c, 4);  c += __shfl_xor(c, 2);  c += __shfl_xor(c, 1);
        if (lane == 0) red[wid] = c;
        __syncthreads();
        if (t == 0) {
            unsigned s = 0;
            for (int w = 0; w < 16; ++w) s += red[w];
            red[16] = s;
        }
        __syncthreads();
        const unsigned r = red[16];
        __syncthreads();
        return r;
    };

    unsigned lo = 0u, hi = 0x40000000u;
    while (hi - lo > 1u) {
        const unsigned mid = (lo + hi) >> 1;
        if (countGE(mid) >= KEEP) lo = mid; else hi = mid;
    }
    const unsigned T    = lo;
    const unsigned cGT  = countGE(T + 1u);
    const unsigned need = KEEP - cGT;

    unsigned pre[16];
    unsigned run = 0;
#pragma unroll
    for (int j = 0; j < 16; ++j) {
        pre[j] = run;
        const unsigned gt = (bits[j] > T) ? 1u : 0u;
        const unsigned eq = (bits[j] == T) ? 1u : 0u;
        run += gt | (eq << 16);
    }
    unsigned inc = run;
#pragma unroll
    for (int off = 1; off < 64; off <<= 1) {
        const unsigned n = __shfl_up(inc, off);
        if (lane >= off) inc += n;
    }
    const unsigned waveExcl = inc - run;
    if (lane == 63) red[wid] = inc;
    __syncthreads();
    if (t == 0) {
        unsigned s = 0;
        for (int w = 0; w < 16; ++w) { const unsigned tmp = red[w]; red[w] = s; s += tmp; }
    }
    __syncthreads();
    const unsigned base = red[wid] + waveExcl;

#pragma unroll
    for (int j = 0; j < 16; ++j) {
        const unsigned pe    = base + pre[j];
        const unsigned tieR  = pe >> 16;
        const unsigned posGT = pe & 0xFFFFu;
        const bool gt = bits[j] > T;
        const bool eq = bits[j] == T;
        if (gt || (eq && tieR < need)) {
            const unsigned pos = posGT + (tieR < need ? tieR : need);
            idxList[(size_t)b * KEEP + pos] = t * 16 + j;
        }
    }
}

// ---------------------------------------------------------------------------
// gather: weighted gather, float4.
// ---------------------------------------------------------------------------
__global__ __launch_bounds__(256) void gather_kernel(
    const float* __restrict__ x, const float* __restrict__ scores,
    const int* __restrict__ idxList, float* __restrict__ out)
{
    const int t = threadIdx.x;
#pragma unroll
    for (int q = 0; q < 4; ++q) {
        const int orow = blockIdx.x * 4 + q;
        const int b    = orow / KEEP;
        const int idx  = idxList[orow];
        const float s  = scores[(size_t)b * N_TOK + idx];
        const float4 v = *(const float4*)(x + (((size_t)b * N_TOK + idx) << 10) + t * 4);
        float4 o;
        o.x = v.x * s; o.y = v.y * s; o.z = v.z * s; o.w = v.w * s;
        *(float4*)(out + ((size_t)orow << 10) + t * 4) = o;
    }
}

// ---------------------------------------------------------------------------
// loss: -mean(|s-0.5|) over 512 block partials, deterministic tree.
// ---------------------------------------------------------------------------
__global__ __launch_bounds__(256) void loss_kernel(
    const float* __restrict__ partials, float* __restrict__ outLoss)
{
    __shared__ float red[256];
    const int t = threadIdx.x;
    red[t] = partials[t] + partials[t + 256];
    __syncthreads();
    for (int off = 128; off > 0; off >>= 1) {
        if (t < off) red[t] += red[t + off];
        __syncthreads();
    }
    if (t == 0) outLoss[0] = -(red[0] / (float)MROWS);
}

extern "C" void kernel_launch(void* const* d_in, const int* in_sizes, int n_in,
                              void* d_out, int out_size, void* d_ws, size_t ws_size,
                              hipStream_t stream)
{
    const float* x  = (const float*)d_in[0];
    const float* W1 = (const float*)d_in[1];
    const float* b1 = (const float*)d_in[2];
    const float* W2 = (const float*)d_in[3];
    const float* b2 = (const float*)d_in[4];
    float* out = (float*)d_out;

    char* ws = (char*)d_ws;
    float* scores   = (float*)ws;                         // 262144 B
    float* partials = (float*)(ws + 262144);              // 2048 B
    int*   idxList  = (int*)(ws + 264192);                // 183488 B
    ushort* Wh      = (ushort*)(ws + 458752);             // 524288 B
    ushort* Wl      = (ushort*)(ws + 983040);             // 524288 B

    prep_kernel<<<NKT, 256, 0, stream>>>(W1, Wh, Wl);
    score_mfma<<<MROWS / 128, 256, 0, stream>>>(x, Wh, Wl, b1, W2, b2, scores, partials);
    loss_kernel<<<1, 256, 0, stream>>>(partials, out + (size_t)BATCH * KEEP * DIM);
    fix_kernel<<<BATCH, 1024, 0, stream>>>(x, W1, b1, W2, b2, scores);
    select_kernel<<<BATCH, 1024, 0, stream>>>(scores, idxList);
    gather_kernel<<<KEEP, 256, 0, stream>>>(x, scores, idxList, out);
}